// Round 6
// baseline (91.028 us; speedup 1.0000x reference)
//
#include <hip/hip_runtime.h>

#define B_TOTAL 1024
#define NGRID   294912
#define NBLK    2048                 // 8 blocks/CU
#define CHUNK   (NGRID / NBLK)       // 144 grid mats per block
#define NTHR    256
#define BPT     4                    // b's per thread: thread t owns b = j*256 + t

// ws: B_TOTAL u64 keys. key = orderable(val)<<32 | ~idx.
// atomicMax => max val; ties -> lowest idx (np.argmax semantics).

__global__ __launch_bounds__(256)
void so3_init_kernel(unsigned long long* __restrict__ ws) {
    int i = blockIdx.x * 256 + threadIdx.x;
    if (i < B_TOTAL) ws[i] = 0ull;   // below any valid key (max trace ~ +3 -> hi >= 0x80...)
}

__global__ __launch_bounds__(NTHR, 8)
void so3_partial_kernel(const float* __restrict__ A,   // [1024][9]
                        const float* __restrict__ G,   // [NGRID][9]
                        unsigned long long* __restrict__ ws)
{
    const int t = threadIdx.x;

    // Wave-uniform chunk base: G rows are read via SCALAR loads (SMEM) into
    // SGPRs — no LDS, no VGPR cost, scalar pipe issue. readfirstlane pins
    // uniformity for the compiler.
    const int n0 = __builtin_amdgcn_readfirstlane(blockIdx.x * CHUNK);
    const float* __restrict__ Gu = G + (size_t)n0 * 9;

    // 4 A-matrices -> 36 registers, fully static indexing (no pointer-cast
    // inits: round-3 lesson — casts demote arrays to scratch).
    float a[BPT][9];
    #pragma unroll
    for (int j = 0; j < BPT; ++j) {
        const float* ap = A + (size_t)(j * NTHR + t) * 9;
        #pragma unroll
        for (int k = 0; k < 9; ++k) a[j][k] = ap[k];
    }

    float best[BPT];
    int   bidx[BPT];
    #pragma unroll
    for (int j = 0; j < BPT; ++j) { best[j] = -1e30f; bidx[j] = 0; }

    // Sweep chunk. g0..g8 are uniform -> SGPRs; each FMA is v_fma(s,v,v).
    // n ascending + strict '>' keeps lowest index on ties.
    #pragma unroll 4
    for (int n = 0; n < CHUNK; ++n) {
        const float* g = Gu + n * 9;
        const float g0 = g[0], g1 = g[1], g2 = g[2],
                    g3 = g[3], g4 = g[4], g5 = g[5],
                    g6 = g[6], g7 = g[7], g8 = g[8];
        const int vn = n0 + n;
        #pragma unroll
        for (int j = 0; j < BPT; ++j) {
            // identical accumulation order since round 2 (bit-identical sims)
            float d;
            d = a[j][0] * g0;
            d = fmaf(a[j][1], g1, d);
            d = fmaf(a[j][2], g2, d);
            d = fmaf(a[j][3], g3, d);
            d = fmaf(a[j][4], g4, d);
            d = fmaf(a[j][5], g5, d);
            d = fmaf(a[j][6], g6, d);
            d = fmaf(a[j][7], g7, d);
            d = fmaf(a[j][8], g8, d);
            if (d > best[j]) { best[j] = d; bidx[j] = vn; }
        }
    }

    // Packed max per owned b. Pre-check: ws is monotone (atomicMax from 0),
    // a plain load only under-reads; "seen >= key" is a safe skip.
    #pragma unroll
    for (int j = 0; j < BPT; ++j) {
        unsigned u = __float_as_uint(best[j]);
        u = (u & 0x80000000u) ? ~u : (u | 0x80000000u);
        unsigned long long key =
            ((unsigned long long)u << 32) | (unsigned)(~bidx[j]);
        unsigned long long seen = ws[j * NTHR + t];
        if (key > seen) atomicMax(&ws[j * NTHR + t], key);
    }
}

__global__ __launch_bounds__(256)
void so3_final_kernel(const float* __restrict__ G,
                      const unsigned long long* __restrict__ ws,
                      float* __restrict__ out)  // [1024] trace, then [1024*9] nearest
{
    int b = blockIdx.x * 256 + threadIdx.x;
    if (b >= B_TOTAL) return;
    unsigned long long key = ws[b];
    unsigned hi = (unsigned)(key >> 32);
    unsigned lo = (unsigned)key;
    unsigned bits = (hi & 0x80000000u) ? (hi ^ 0x80000000u) : ~hi;
    int idx = (int)(~lo);
    out[b] = __uint_as_float(bits);
    const float* g = G + (size_t)idx * 9;
    float* o = out + B_TOTAL + (size_t)b * 9;
    #pragma unroll
    for (int k = 0; k < 9; ++k) o[k] = g[k];
}

extern "C" void kernel_launch(void* const* d_in, const int* in_sizes, int n_in,
                              void* d_out, int out_size, void* d_ws, size_t ws_size,
                              hipStream_t stream) {
    const float* A = (const float*)d_in[0];   // rotMat [1024,3,3] fp32
    const float* G = (const float*)d_in[1];   // output_rotmats [294912,3,3] fp32
    float* out = (float*)d_out;
    unsigned long long* ws = (unsigned long long*)d_ws;  // 8 KB

    hipLaunchKernelGGL(so3_init_kernel,    dim3(4),    dim3(256), 0, stream, ws);
    hipLaunchKernelGGL(so3_partial_kernel, dim3(NBLK), dim3(NTHR), 0, stream, A, G, ws);
    hipLaunchKernelGGL(so3_final_kernel,   dim3(4),    dim3(256), 0, stream, G, ws, out);
}